// Round 1
// baseline (5256.352 us; speedup 1.0000x reference)
//
#include <hip/hip_runtime.h>
#include <hip/hip_fp16.h>

typedef _Float16 h16;
typedef _Float16 v8h  __attribute__((ext_vector_type(8)));
typedef float    v4f  __attribute__((ext_vector_type(4)));

struct PParams {
  const float* x;                 // [64][512][256] fp32
  const float* Wih[4];            // [2048][KIN]
  const float* Whh[4];            // [2048][512]
  const float* bih[4];
  const float* bhh[4];
  h16* s[4];                      // streams: l=0..2 [512][64][512], l=3 [2][64][512]
  unsigned int* flags;            // [16 groups][64 wave slots], monotonic counters
};

__device__ inline float fsigmoid(float x){
  float e = __builtin_amdgcn_exp2f(-1.4426950408889634f * __builtin_fabsf(x));
  float r = __builtin_amdgcn_rcpf(1.0f + e);
  return x >= 0.f ? r : e * r;
}
__device__ inline float ftanhf(float x){
  float e = __builtin_amdgcn_exp2f(-2.8853900817779268f * __builtin_fabsf(x));
  float t = (1.0f - e) * __builtin_amdgcn_rcpf(1.0f + e);
  return x >= 0.f ? t : -t;
}

// Fine-grained agent-coherent ops: write-through to L3 / read-through past the
// non-coherent per-XCD L2. No whole-cache wbl2/inv fences anywhere.
__device__ inline unsigned int fload(const unsigned int* p){
  return __hip_atomic_load(p, __ATOMIC_RELAXED, __HIP_MEMORY_SCOPE_AGENT);
}
__device__ inline unsigned long long cload64(const void* p){
  return __hip_atomic_load((const unsigned long long*)p, __ATOMIC_RELAXED,
                           __HIP_MEMORY_SCOPE_AGENT);
}
__device__ inline void cstore32(void* p, unsigned int v){
  __hip_atomic_store((unsigned int*)p, v, __ATOMIC_RELAXED, __HIP_MEMORY_SCOPE_AGENT);
}

// Wave-parallel group wait: 64 producer-wave slots per (layer,bg) group, one
// slot per lane (256 B = 4 cache lines, one coalesced gather per poll).
__device__ inline void wait_group(const unsigned int* slots, unsigned int tgt, int lane){
  int it = 0;
  while (true){
    unsigned int v = fload(slots + lane);
    if (__all(v >= tgt)) break;
    __builtin_amdgcn_s_sleep(1);
    if (++it > (1 << 21)) break;   // safety valve: never hang the harness
  }
}

// One LSTM layer slice: this wave owns 8 hidden units x 4 gates for 16 batches.
// Barrier-free: no LDS, no __syncthreads. A-operand fragments are loaded
// DIRECTLY from L3 (lane fragment = 16 contiguous bytes of [batch][unit]
// stream), so there is no staging, no LDS bank conflict, no barrier.
// The W_ih GEMM for step t+1 is computed right after publishing h(t), hiding
// its load latency inside the flag round-trip window of the recurrence.
template<int KIN, bool XSRC>
__device__ void run_layer(const float* __restrict__ Wih, const float* __restrict__ Whh,
                          const float* __restrict__ bih, const float* __restrict__ bhh,
                          const float* __restrict__ xsrc,
                          const h16* __restrict__ src,
                          h16* __restrict__ dst, int dstMask,
                          unsigned int* flagSelf, const unsigned int* flagSrc,
                          int rg, int bg)
{
  const int tid  = threadIdx.x;
  const int wv   = tid >> 6;
  const int lane = tid & 63;
  const int KI   = KIN / 32;

  const int n16  = lane & 15;
  const int unit = rg*32 + wv*8 + (n16 & 7);
  const int ksub = ((lane >> 4) & 3) * 8;
  const int row0 = ((n16 >> 3)    ) * 512 + unit;   // gate i (n<8) / f (n>=8)
  const int row1 = ((n16 >> 3) + 2) * 512 + unit;   // gate g / o

  // ---- prologue: load weight slices into register fragments (one-time).
  // 256 VGPR-equivalents of weights -> compiler parks them in AGPRs
  // (gfx950 unified file; MFMA reads B directly from AGPR).
  v8h wihf[KI][2];
  #pragma unroll
  for (int kk = 0; kk < KI; ++kk){
    #pragma unroll
    for (int j = 0; j < 2; ++j){
      const float* p = Wih + (size_t)(j ? row1 : row0) * KIN + kk*32 + ksub;
      v8h fr;
      #pragma unroll
      for (int e = 0; e < 8; ++e) fr[e] = (h16)p[e];
      wihf[kk][j] = fr;
    }
  }
  v8h whhf[16][2];
  #pragma unroll
  for (int kk = 0; kk < 16; ++kk){
    #pragma unroll
    for (int j = 0; j < 2; ++j){
      const float* p = Whh + (size_t)(j ? row1 : row0) * 512 + kk*32 + ksub;
      v8h fr;
      #pragma unroll
      for (int e = 0; e < 8; ++e) fr[e] = (h16)p[e];
      whhf[kk][j] = fr;
    }
  }
  const float bias0 = bih[row0] + bhh[row0];
  const float bias1 = bih[row1] + bhh[row1];
  float c[4] = {0.f, 0.f, 0.f, 0.f};
  const bool hi   = (lane & 8) != 0;
  const int slot  = rg*4 + wv;          // this wave's flag slot (0..63)
  const int abatch = bg*16 + n16;       // A-fragment batch row for this lane

  // 4 independent accumulator chains (even/odd kk) to cover dependent-MFMA
  // latency at 1 wave/SIMD. Gates read e+o.
  v4f a0e = {0,0,0,0}, a0o = {0,0,0,0}, a1e = {0,0,0,0}, a1o = {0,0,0,0};

  // W_ih GEMM for timestep t, accumulating into the 4 chains. Lane fragment =
  // 16 contiguous bytes, loaded straight from global (L3) memory.
  auto wih_tile = [&](int t, v4f& e0, v4f& o0, v4f& e1, v4f& o1){
    if constexpr (XSRC){
      const float* xp = xsrc + ((size_t)abatch*512 + t)*256 + ksub;
      #pragma unroll
      for (int kk = 0; kk < KI; ++kk){
        float4 v0 = *(const float4*)(xp + kk*32);
        float4 v1 = *(const float4*)(xp + kk*32 + 4);
        v8h a = {(h16)v0.x,(h16)v0.y,(h16)v0.z,(h16)v0.w,
                 (h16)v1.x,(h16)v1.y,(h16)v1.z,(h16)v1.w};
        if (kk & 1){
          o0 = __builtin_amdgcn_mfma_f32_16x16x32_f16(a, wihf[kk][0], o0, 0, 0, 0);
          o1 = __builtin_amdgcn_mfma_f32_16x16x32_f16(a, wihf[kk][1], o1, 0, 0, 0);
        } else {
          e0 = __builtin_amdgcn_mfma_f32_16x16x32_f16(a, wihf[kk][0], e0, 0, 0, 0);
          e1 = __builtin_amdgcn_mfma_f32_16x16x32_f16(a, wihf[kk][1], e1, 0, 0, 0);
        }
      }
    } else {
      const h16* sp = src + ((size_t)t*64 + abatch)*512 + ksub;
      #pragma unroll
      for (int kk = 0; kk < KI; ++kk){
        union { unsigned long long u[2]; v8h h; } tmp;
        tmp.u[0] = cload64(sp + kk*32);
        tmp.u[1] = cload64(sp + kk*32 + 4);
        if (kk & 1){
          o0 = __builtin_amdgcn_mfma_f32_16x16x32_f16(tmp.h, wihf[kk][0], o0, 0, 0, 0);
          o1 = __builtin_amdgcn_mfma_f32_16x16x32_f16(tmp.h, wihf[kk][1], o1, 0, 0, 0);
        } else {
          e0 = __builtin_amdgcn_mfma_f32_16x16x32_f16(tmp.h, wihf[kk][0], e0, 0, 0, 0);
          e1 = __builtin_amdgcn_mfma_f32_16x16x32_f16(tmp.h, wihf[kk][1], e1, 0, 0, 0);
        }
      }
    }
  };

  // Wih(0): for layers >= 1 wait for the layer below to publish t=0 (flag 1).
  if constexpr (!XSRC) wait_group(flagSrc, 1u, lane);
  wih_tile(0, a0e, a0o, a1e, a1o);

  #pragma unroll 1
  for (int t = 0; t < 512; ++t){
    // ===== recurrence: wait for h(t-1) from all 64 producer waves, then
    // load A fragments straight from L3 and run the W_hh chain.
    // t=0: h(-1)=0 contributes nothing -> skip entirely.
    if (t > 0){
      wait_group(flagSelf, (unsigned)t, lane);
      const h16* hp = dst + (size_t)((t-1) & dstMask) * 64 * 512
                          + (size_t)abatch * 512 + ksub;
      #pragma unroll
      for (int kk = 0; kk < 16; ++kk){
        union { unsigned long long u[2]; v8h h; } tmp;
        tmp.u[0] = cload64(hp + kk*32);
        tmp.u[1] = cload64(hp + kk*32 + 4);
        if (kk & 1){
          a0o = __builtin_amdgcn_mfma_f32_16x16x32_f16(tmp.h, whhf[kk][0], a0o, 0, 0, 0);
          a1o = __builtin_amdgcn_mfma_f32_16x16x32_f16(tmp.h, whhf[kk][1], a1o, 0, 0, 0);
        } else {
          a0e = __builtin_amdgcn_mfma_f32_16x16x32_f16(tmp.h, whhf[kk][0], a0e, 0, 0, 0);
          a1e = __builtin_amdgcn_mfma_f32_16x16x32_f16(tmp.h, whhf[kk][1], a1e, 0, 0, 0);
        }
      }
    }

    // ---- gates: lane L holds (i|f) in acc0, (g|o) in acc1; partner is L^8
    h16* drow = dst + (size_t)(t & dstMask) * 64 * 512;
    #pragma unroll
    for (int r = 0; r < 4; ++r){
      float z0 = a0e[r] + a0o[r] + bias0;
      float z1 = a1e[r] + a1o[r] + bias1;
      float p0 = __shfl_xor(z0, 8, 64);
      float p1 = __shfl_xor(z1, 8, 64);
      float iv = hi ? p0 : z0;
      float fv = hi ? z0 : p0;
      float gv = hi ? p1 : z1;
      float ov = hi ? z1 : p1;
      iv = fsigmoid(iv); fv = fsigmoid(fv); ov = fsigmoid(ov);
      gv = ftanhf(gv);
      c[r] = fv * c[r] + iv * gv;
      float hval = ov * ftanhf(c[r]);
      h16 hh = (h16)hval;
      unsigned int mine = (unsigned int)__builtin_bit_cast(unsigned short, hh);
      unsigned int partner = (unsigned int)__shfl_xor((int)mine, 1, 64);
      if (!hi && !(n16 & 1)){
        int batch = bg*16 + ((lane >> 4) << 2) + r;
        // packed 2-unit write-through store -> visible in L3
        cstore32((void*)(drow + (size_t)batch*512 + unit), mine | (partner << 16));
      }
    }

    // per-wave drain of write-through h stores to L3, then publish our slot.
    asm volatile("s_waitcnt vmcnt(0)" ::: "memory");
    if (lane == 0) cstore32(flagSelf + slot, (unsigned)(t + 1));

    // ===== prefetch phase: W_ih GEMM for t+1 fills the flag round-trip
    // latency window of the recurrence.
    if (t < 511){
      a0e = (v4f){0,0,0,0}; a0o = (v4f){0,0,0,0};
      a1e = (v4f){0,0,0,0}; a1o = (v4f){0,0,0,0};
      if constexpr (!XSRC) wait_group(flagSrc, (unsigned)(t + 2), lane);
      wih_tile(t + 1, a0e, a0o, a1e, a1o);
    }
  }
}

__global__ __launch_bounds__(256, 1) void lstm_persist(PParams p){
  const int bx = blockIdx.x;
  const int l  = bx >> 6;
  const int rg = (bx >> 2) & 15;
  const int bg = bx & 3;
  unsigned int* fl = p.flags + (size_t)(l*4 + bg) * 64;
  if (l == 0){
    run_layer<256, true >(p.Wih[0], p.Whh[0], p.bih[0], p.bhh[0], p.x, nullptr,
                          p.s[0], 511, fl, nullptr, rg, bg);
  } else {
    const unsigned int* fs = p.flags + (size_t)((l-1)*4 + bg) * 64;
    run_layer<512, false>(p.Wih[l], p.Whh[l], p.bih[l], p.bhh[l], nullptr, p.s[l-1],
                          p.s[l], (l == 3) ? 1 : 511, fl, fs, rg, bg);
  }
}

__global__ void head_k(const h16* __restrict__ h3, const float* __restrict__ Wo,
                       const float* __restrict__ bo, float* __restrict__ out){
  const int b = blockIdx.x;
  const int lane = threadIdx.x;
  float s = 0.f;
  for (int u = lane; u < 512; u += 64)
    s += (float)h3[(size_t)b * 512 + u] * Wo[u];
  #pragma unroll
  for (int off = 32; off; off >>= 1) s += __shfl_down(s, off, 64);
  if (lane == 0) out[b] = s + bo[0];
}

__global__ void zero_out_k(float* out, int n){
  int i = blockIdx.x * 64 + threadIdx.x;
  if (i < n) out[i] = 0.f;
}

extern "C" void kernel_launch(void* const* d_in, const int* in_sizes, int n_in,
                              void* d_out, int out_size, void* d_ws, size_t ws_size,
                              hipStream_t stream){
  PParams p;
  p.x = (const float*)d_in[0];
  for (int l = 0; l < 4; ++l){
    p.Wih[l] = (const float*)d_in[1 + 4*l + 0];
    p.Whh[l] = (const float*)d_in[1 + 4*l + 1];
    p.bih[l] = (const float*)d_in[1 + 4*l + 2];
    p.bhh[l] = (const float*)d_in[1 + 4*l + 3];
  }
  const float* Wo = (const float*)d_in[17];
  const float* bo = (const float*)d_in[18];

  const size_t FLAG_BYTES = 16 * 64 * sizeof(unsigned int);       // 4 KB
  const size_t SBYTES     = (size_t)512 * 64 * 512 * 2;           // 32 MB per full stream
  const size_t NEED       = 32768 + 3 * SBYTES + (size_t)2 * 64 * 512 * 2;

  if (ws_size < NEED){
    zero_out_k<<<dim3(1), dim3(64), 0, stream>>>((float*)d_out, out_size);
    return;
  }

  char* ws = (char*)d_ws;
  p.flags = (unsigned int*)ws;
  size_t off = 32768;
  for (int l = 0; l < 3; ++l){ p.s[l] = (h16*)(ws + off); off += SBYTES; }
  p.s[3] = (h16*)(ws + off);

  hipMemsetAsync(p.flags, 0, FLAG_BYTES, stream);

  void* args[] = { &p };
  hipError_t e = hipLaunchCooperativeKernel((void*)lstm_persist, dim3(256), dim3(256),
                                            args, 0, stream);
  if (e != hipSuccess){
    // fallback: plain launch; 256 blocks @ 1 wg/CU co-reside on 256 CUs
    lstm_persist<<<dim3(256), dim3(256), 0, stream>>>(p);
  }

  // final timestep t=511 lives in s3 buffer (511 & 1) == 1
  head_k<<<dim3(64), dim3(64), 0, stream>>>(p.s[3] + (size_t)64 * 512, Wo, bo, (float*)d_out);
}

// Round 2
// 2546.236 us; speedup vs baseline: 2.0644x; 2.0644x over previous
//
#include <hip/hip_runtime.h>
#include <hip/hip_fp16.h>

typedef _Float16 h16;
typedef _Float16 v8h  __attribute__((ext_vector_type(8)));
typedef float    v4f  __attribute__((ext_vector_type(4)));

struct PParams {
  const float* x;                 // [64][512][256] fp32
  const float* Wih[4];            // [2048][KIN]
  const float* Whh[4];            // [2048][512]
  const float* bih[4];
  const float* bhh[4];
  h16* s[4];                      // streams: l=0..2 [512][64][512], l=3 [2][64][512]
  unsigned int* flags;            // [16 groups][64 wave slots], monotonic t+1
};

__device__ inline float fsigmoid(float x){
  float e = __builtin_amdgcn_exp2f(-1.4426950408889634f * __builtin_fabsf(x));
  float r = __builtin_amdgcn_rcpf(1.0f + e);
  return x >= 0.f ? r : e * r;
}
__device__ inline float ftanhf(float x){
  float e = __builtin_amdgcn_exp2f(-2.8853900817779268f * __builtin_fabsf(x));
  float t = (1.0f - e) * __builtin_amdgcn_rcpf(1.0f + e);
  return x >= 0.f ? t : -t;
}

// Fine-grained agent-coherent ops (sc0/sc1): write-through to L3 / read-through
// past the non-coherent per-XCD L2. No whole-cache wbl2/inv fences anywhere.
__device__ inline unsigned int fload(const unsigned int* p){
  return __hip_atomic_load(p, __ATOMIC_RELAXED, __HIP_MEMORY_SCOPE_AGENT);
}
__device__ inline unsigned long long cload64(const void* p){
  return __hip_atomic_load((const unsigned long long*)p, __ATOMIC_RELAXED,
                           __HIP_MEMORY_SCOPE_AGENT);
}
__device__ inline void cstore32(void* p, unsigned int v){
  __hip_atomic_store((unsigned int*)p, v, __ATOMIC_RELAXED, __HIP_MEMORY_SCOPE_AGENT);
}

// Wave-parallel group wait: 64 producer-wave slots per (layer,bg) group, one
// slot per lane (256 B = 4 cache lines, one coalesced gather per poll).
// No atomics, no single-lane poll, no broadcast barrier.
__device__ inline void wait_slots(const unsigned int* slots, unsigned int tgt, int lane){
  unsigned int v = fload(slots + lane);
  if (__all(v >= tgt)) return;
  int it = 0;
  do {
    __builtin_amdgcn_s_sleep(1);
    v = fload(slots + lane);
    if (++it > (1 << 20)) break;   // safety valve: never hang the harness
  } while (!__all(v >= tgt));
}

// One LSTM layer slice: this wg owns 32 hidden units x 4 gates for 16 batches.
// Weights live in VGPR/AGPR as MFMA B-fragments; c stays in fp32 registers.
// Per step: stage src(t)->LDS, bar, W_ih MFMAs (self-flag pre-check load in
// flight underneath), resolve self wait, stage h(t-1)->LDS, bar, W_hh MFMAs,
// gates, per-wave drain + slot publish. Exactly 2 barriers per step: the two
// LDS write->read hazards. All other round-0 barriers are implied rendezvous.
template<int KIN, bool XSRC>
__device__ void run_layer(const float* __restrict__ Wih, const float* __restrict__ Whh,
                          const float* __restrict__ bih, const float* __restrict__ bhh,
                          const float* __restrict__ xsrc,
                          const h16* __restrict__ src,
                          h16* __restrict__ dst, int dstMask,
                          unsigned int* flagSelf, const unsigned int* flagSrc,
                          int rg, int bg, h16* A)
{
  const int tid  = threadIdx.x;
  const int wv   = tid >> 6;
  const int lane = tid & 63;
  const int ISTR = KIN + 8;       // padded LDS row stride (halves)
  const int HOFF = 8320;          // h-region offset (halves), stride 520
  const int KI   = KIN / 32;

  const int n16  = lane & 15;
  const int unit = rg*32 + wv*8 + (n16 & 7);
  const int ksub = ((lane >> 4) & 3) * 8;
  const int row0 = ((n16 >> 3)    ) * 512 + unit;   // gate i (n<8) / f (n>=8)
  const int row1 = ((n16 >> 3) + 2) * 512 + unit;   // gate g / o

  // ---- prologue: load weight slices into register fragments (one-time)
  v8h wihf[KI][2];
  #pragma unroll
  for (int kk = 0; kk < KI; ++kk){
    #pragma unroll
    for (int j = 0; j < 2; ++j){
      const float* p = Wih + (size_t)(j ? row1 : row0) * KIN + kk*32 + ksub;
      v8h fr;
      #pragma unroll
      for (int e = 0; e < 8; ++e) fr[e] = (h16)p[e];
      wihf[kk][j] = fr;
    }
  }
  v8h whhf[16][2];
  #pragma unroll
  for (int kk = 0; kk < 16; ++kk){
    #pragma unroll
    for (int j = 0; j < 2; ++j){
      const float* p = Whh + (size_t)(j ? row1 : row0) * 512 + kk*32 + ksub;
      v8h fr;
      #pragma unroll
      for (int e = 0; e < 8; ++e) fr[e] = (h16)p[e];
      whhf[kk][j] = fr;
    }
  }
  const float bias0 = bih[row0] + bhh[row0];
  const float bias1 = bih[row1] + bhh[row1];
  float c[4] = {0.f, 0.f, 0.f, 0.f};
  const bool hi   = (lane & 8) != 0;
  const int  slot = rg*4 + wv;          // this wave's flag slot (0..63)

  #pragma unroll 1
  for (int t = 0; t < 512; ++t){
    // ================= phase 1: input from layer below =================
    if constexpr (!XSRC) wait_slots(flagSrc, (unsigned)(t + 1), lane);

    if constexpr (XSRC){
      #pragma unroll
      for (int i = 0; i < 2; ++i){
        int q = tid + i*256;
        int row = q >> 5, col = q & 31;          // 32 chunks x 8 halves per row
        const float* xp = xsrc + ((size_t)(bg*16 + row)*512 + t)*256 + col*8;
        float4 v0 = *(const float4*)(xp);
        float4 v1 = *(const float4*)(xp + 4);
        v8h o = {(h16)v0.x,(h16)v0.y,(h16)v0.z,(h16)v0.w,
                 (h16)v1.x,(h16)v1.y,(h16)v1.z,(h16)v1.w};
        *(v8h*)(A + row*ISTR + col*8) = o;
      }
    } else {
      unsigned long long a0[4], a1[4];
      #pragma unroll
      for (int i = 0; i < 4; ++i){
        int q = tid + i*256;
        int row = q >> 6, col = q & 63;          // 64 chunks x 8 halves per row
        const h16* sp = src + ((size_t)t*64 + bg*16 + row)*512 + col*8;
        a0[i] = cload64(sp);
        a1[i] = cload64(sp + 4);
      }
      #pragma unroll
      for (int i = 0; i < 4; ++i){
        int q = tid + i*256;
        int row = q >> 6, col = q & 63;
        union { unsigned long long u[2]; v8h h; } tmp;
        tmp.u[0] = a0[i]; tmp.u[1] = a1[i];
        *(v8h*)(A + row*ISTR + col*8) = tmp.h;
      }
    }
    __syncthreads();   // hazard: stage-in writes -> W_ih reads

    // non-blocking self-flag pre-check: load issued here, resolved after the
    // W_ih MFMA chain -> L3 poll latency hides behind compute.
    unsigned int selfv = 0xffffffffu;
    if (t > 0) selfv = fload(flagSelf + lane);

    v4f a0e = {0,0,0,0}, a0o = {0,0,0,0};
    v4f a1e = {0,0,0,0}, a1o = {0,0,0,0};
    const h16* Ain = A + n16*ISTR + ksub;
    #pragma unroll
    for (int kk = 0; kk < KI; ++kk){
      v8h a = *(const v8h*)(Ain + kk*32);
      if (kk & 1){
        a0o = __builtin_amdgcn_mfma_f32_16x16x32_f16(a, wihf[kk][0], a0o, 0, 0, 0);
        a1o = __builtin_amdgcn_mfma_f32_16x16x32_f16(a, wihf[kk][1], a1o, 0, 0, 0);
      } else {
        a0e = __builtin_amdgcn_mfma_f32_16x16x32_f16(a, wihf[kk][0], a0e, 0, 0, 0);
        a1e = __builtin_amdgcn_mfma_f32_16x16x32_f16(a, wihf[kk][1], a1e, 0, 0, 0);
      }
    }

    // ================= phase 2: recurrence =================
    if (t > 0 && !__all(selfv >= (unsigned)t))
      wait_slots(flagSelf, (unsigned)t, lane);

    if (t == 0){
      #pragma unroll
      for (int i = 0; i < 4; ++i){
        int q = tid + i*256;
        int row = q >> 6, col = q & 63;
        union { unsigned long long u[2]; v8h h; } tmp;
        tmp.u[0] = 0ull; tmp.u[1] = 0ull;
        *(v8h*)(A + HOFF + row*520 + col*8) = tmp.h;
      }
    } else {
      const h16* hsrc = dst + (size_t)((t-1) & dstMask) * 64 * 512;
      unsigned long long a0[4], a1[4];
      #pragma unroll
      for (int i = 0; i < 4; ++i){
        int q = tid + i*256;
        int row = q >> 6, col = q & 63;
        const h16* sp = hsrc + (size_t)(bg*16 + row)*512 + col*8;
        a0[i] = cload64(sp);
        a1[i] = cload64(sp + 4);
      }
      #pragma unroll
      for (int i = 0; i < 4; ++i){
        int q = tid + i*256;
        int row = q >> 6, col = q & 63;
        union { unsigned long long u[2]; v8h h; } tmp;
        tmp.u[0] = a0[i]; tmp.u[1] = a1[i];
        *(v8h*)(A + HOFF + row*520 + col*8) = tmp.h;
      }
    }
    __syncthreads();   // hazard: stage-h writes -> W_hh reads

    const h16* Ah = A + HOFF + n16*520 + ksub;
    #pragma unroll
    for (int kk = 0; kk < 16; ++kk){
      v8h a = *(const v8h*)(Ah + kk*32);
      if (kk & 1){
        a0o = __builtin_amdgcn_mfma_f32_16x16x32_f16(a, whhf[kk][0], a0o, 0, 0, 0);
        a1o = __builtin_amdgcn_mfma_f32_16x16x32_f16(a, whhf[kk][1], a1o, 0, 0, 0);
      } else {
        a0e = __builtin_amdgcn_mfma_f32_16x16x32_f16(a, whhf[kk][0], a0e, 0, 0, 0);
        a1e = __builtin_amdgcn_mfma_f32_16x16x32_f16(a, whhf[kk][1], a1e, 0, 0, 0);
      }
    }

    // ---- gates: lane L holds (i|f) in acc0, (g|o) in acc1; partner is L^8
    h16* drow = dst + (size_t)(t & dstMask) * 64 * 512;
    #pragma unroll
    for (int r = 0; r < 4; ++r){
      float z0 = a0e[r] + a0o[r] + bias0;
      float z1 = a1e[r] + a1o[r] + bias1;
      float p0 = __shfl_xor(z0, 8, 64);
      float p1 = __shfl_xor(z1, 8, 64);
      float iv = hi ? p0 : z0;
      float fv = hi ? z0 : p0;
      float gv = hi ? p1 : z1;
      float ov = hi ? z1 : p1;
      iv = fsigmoid(iv); fv = fsigmoid(fv); ov = fsigmoid(ov);
      gv = ftanhf(gv);
      c[r] = fv * c[r] + iv * gv;
      float hval = ov * ftanhf(c[r]);
      h16 hh = (h16)hval;
      unsigned int mine = (unsigned int)__builtin_bit_cast(unsigned short, hh);
      unsigned int partner = (unsigned int)__shfl_xor((int)mine, 1, 64);
      if (!hi && !(n16 & 1)){
        int batch = bg*16 + ((lane >> 4) << 2) + r;
        // packed 2-unit write-through store (sc0 sc1) -> visible in L3
        cstore32((void*)(drow + (size_t)batch*512 + unit), mine | (partner << 16));
      }
    }

    // per-wave drain of this wave's write-through h stores, then publish slot.
    asm volatile("s_waitcnt vmcnt(0)" ::: "memory");
    if (lane == 0) cstore32(flagSelf + slot, (unsigned)(t + 1));
  }
}

__global__ __launch_bounds__(256, 1) void lstm_persist(PParams p){
  __shared__ h16 A[16640];   // 33,280 B: in-region 16x520 + h-region 16x520
  const int bx = blockIdx.x;
  const int l  = bx >> 6;
  const int rg = (bx >> 2) & 15;
  const int bg = bx & 3;
  unsigned int* fl = p.flags + (size_t)(l*4 + bg) * 64;
  if (l == 0){
    run_layer<256, true >(p.Wih[0], p.Whh[0], p.bih[0], p.bhh[0], p.x, nullptr,
                          p.s[0], 511, fl, nullptr, rg, bg, A);
  } else {
    const unsigned int* fs = p.flags + (size_t)((l-1)*4 + bg) * 64;
    run_layer<512, false>(p.Wih[l], p.Whh[l], p.bih[l], p.bhh[l], nullptr, p.s[l-1],
                          p.s[l], (l == 3) ? 1 : 511, fl, fs, rg, bg, A);
  }
}

__global__ void head_k(const h16* __restrict__ h3, const float* __restrict__ Wo,
                       const float* __restrict__ bo, float* __restrict__ out){
  const int b = blockIdx.x;
  const int lane = threadIdx.x;
  float s = 0.f;
  for (int u = lane; u < 512; u += 64)
    s += (float)h3[(size_t)b * 512 + u] * Wo[u];
  #pragma unroll
  for (int off = 32; off; off >>= 1) s += __shfl_down(s, off, 64);
  if (lane == 0) out[b] = s + bo[0];
}

__global__ void zero_out_k(float* out, int n){
  int i = blockIdx.x * 64 + threadIdx.x;
  if (i < n) out[i] = 0.f;
}

extern "C" void kernel_launch(void* const* d_in, const int* in_sizes, int n_in,
                              void* d_out, int out_size, void* d_ws, size_t ws_size,
                              hipStream_t stream){
  PParams p;
  p.x = (const float*)d_in[0];
  for (int l = 0; l < 4; ++l){
    p.Wih[l] = (const float*)d_in[1 + 4*l + 0];
    p.Whh[l] = (const float*)d_in[1 + 4*l + 1];
    p.bih[l] = (const float*)d_in[1 + 4*l + 2];
    p.bhh[l] = (const float*)d_in[1 + 4*l + 3];
  }
  const float* Wo = (const float*)d_in[17];
  const float* bo = (const float*)d_in[18];

  const size_t FLAG_BYTES = 16 * 64 * sizeof(unsigned int);       // 4 KB
  const size_t SBYTES     = (size_t)512 * 64 * 512 * 2;           // 32 MB per full stream
  const size_t NEED       = 32768 + 3 * SBYTES + (size_t)2 * 64 * 512 * 2;

  if (ws_size < NEED){
    zero_out_k<<<dim3(1), dim3(64), 0, stream>>>((float*)d_out, out_size);
    return;
  }

  char* ws = (char*)d_ws;
  p.flags = (unsigned int*)ws;
  size_t off = 32768;
  for (int l = 0; l < 3; ++l){ p.s[l] = (h16*)(ws + off); off += SBYTES; }
  p.s[3] = (h16*)(ws + off);

  hipMemsetAsync(p.flags, 0, FLAG_BYTES, stream);

  void* args[] = { &p };
  hipError_t e = hipLaunchCooperativeKernel((void*)lstm_persist, dim3(256), dim3(256),
                                            args, 0, stream);
  if (e != hipSuccess){
    // fallback: plain launch; 256 blocks @ 1 wg/CU co-reside on 256 CUs
    lstm_persist<<<dim3(256), dim3(256), 0, stream>>>(p);
  }

  // final timestep t=511 lives in s3 buffer (511 & 1) == 1
  head_k<<<dim3(64), dim3(64), 0, stream>>>(p.s[3] + (size_t)64 * 512, Wo, bo, (float*)d_out);
}

// Round 4
// 1989.142 us; speedup vs baseline: 2.6425x; 1.2801x over previous
//
#include <hip/hip_runtime.h>
#include <hip/hip_fp16.h>

typedef _Float16 h16;
typedef _Float16 v8h  __attribute__((ext_vector_type(8)));
typedef float    v4f  __attribute__((ext_vector_type(4)));

// all-16-producers-done pattern: 16 bytes each == 1
#define FPAT 0x0101010101010101ull

struct PParams {
  const float* x;                 // [64][512][256] fp32
  const float* Wih[4];            // [2048][KIN]
  const float* Whh[4];            // [2048][512]
  const float* bih[4];
  const float* bhh[4];
  h16* s[4];                      // streams: l=0..2 [512][64][512], l=3 [2][64][512]
  unsigned char* flags;           // [16 groups][512 t][16 wg] bytes, 0 -> 1
};

__device__ inline float fsigmoid(float x){
  float e = __builtin_amdgcn_exp2f(-1.4426950408889634f * __builtin_fabsf(x));
  float r = __builtin_amdgcn_rcpf(1.0f + e);
  return x >= 0.f ? r : e * r;
}
__device__ inline float ftanhf(float x){
  float e = __builtin_amdgcn_exp2f(-2.8853900817779268f * __builtin_fabsf(x));
  float t = (1.0f - e) * __builtin_amdgcn_rcpf(1.0f + e);
  return x >= 0.f ? t : -t;
}

// Fine-grained agent-coherent ops (sc0/sc1): write-through to L3 / read-through
// past the non-coherent per-XCD L2. No whole-cache wbl2/inv fences anywhere.
__device__ inline unsigned long long cload64(const void* p){
  return __hip_atomic_load((const unsigned long long*)p, __ATOMIC_RELAXED,
                           __HIP_MEMORY_SCOPE_AGENT);
}
__device__ inline void cstore32(void* p, unsigned int v){
  __hip_atomic_store((unsigned int*)p, v, __ATOMIC_RELAXED, __HIP_MEMORY_SCOPE_AGENT);
}
__device__ inline void cstore8(void* p, unsigned char v){
  __hip_atomic_store((unsigned char*)p, v, __ATOMIC_RELAXED, __HIP_MEMORY_SCOPE_AGENT);
}

// Poll a 16-byte flag vector (one byte per producer wg). Bytes are only ever
// 0 or 1, so (a & b) == FPAT  <=>  all 16 bytes == 1. Single-lane poll, two
// coalesced 8B agent loads — same traffic shape as round-0's counter poll,
// but producers publish with independent byte STORES (no serialized RMW chain
// on the flag line, no atomic return round-trip).
__device__ inline void wait_flag16(const unsigned long long* f){
  int it = 0;
  while (true){
    unsigned long long a = cload64(f);
    unsigned long long b = cload64(f + 1);
    if ((a & b) == FPAT) break;
    __builtin_amdgcn_s_sleep(1);
    if (++it > (1 << 21)) break;   // safety valve: never hang the harness
  }
}

// One LSTM layer slice: this wg owns 32 hidden units x 4 gates for 16 batches.
// Weights live in VGPRs as MFMA B-fragments. c stays in fp32 registers.
// Step = src-phase (stage in(t), W_ih MFMAs) then self-phase (stage h(t-1),
// W_hh MFMAs, gates, publish h). Self-flag pre-checked before the W_ih chain
// so its L3 latency hides behind compute. Structure identical to the 1977us
// baseline except the flag encoding (per-wg bytes instead of atomic counter).
template<int KIN, bool XSRC>
__device__ void run_layer(const float* __restrict__ Wih, const float* __restrict__ Whh,
                          const float* __restrict__ bih, const float* __restrict__ bhh,
                          const float* __restrict__ xsrc,
                          const h16* __restrict__ src,
                          h16* __restrict__ dst, int dstMask,
                          unsigned char* flagSelf, const unsigned char* flagSrc,
                          int rg, int bg, h16* A)
{
  const int tid  = threadIdx.x;
  const int wv   = tid >> 6;
  const int lane = tid & 63;
  const int ISTR = KIN + 8;       // padded LDS row stride (halves)
  const int HOFF = 8320;          // h-region offset (halves), stride 520
  const int KI   = KIN / 32;

  const int n16  = lane & 15;
  const int unit = rg*32 + wv*8 + (n16 & 7);
  const int ksub = ((lane >> 4) & 3) * 8;
  const int row0 = ((n16 >> 3)    ) * 512 + unit;   // gate i (n<8) / f (n>=8)
  const int row1 = ((n16 >> 3) + 2) * 512 + unit;   // gate g / o

  // ---- prologue: load weight slices into register fragments (one-time)
  v8h wihf[KI][2];
  #pragma unroll
  for (int kk = 0; kk < KI; ++kk){
    #pragma unroll
    for (int j = 0; j < 2; ++j){
      const float* p = Wih + (size_t)(j ? row1 : row0) * KIN + kk*32 + ksub;
      v8h fr;
      #pragma unroll
      for (int e = 0; e < 8; ++e) fr[e] = (h16)p[e];
      wihf[kk][j] = fr;
    }
  }
  v8h whhf[16][2];
  #pragma unroll
  for (int kk = 0; kk < 16; ++kk){
    #pragma unroll
    for (int j = 0; j < 2; ++j){
      const float* p = Whh + (size_t)(j ? row1 : row0) * 512 + kk*32 + ksub;
      v8h fr;
      #pragma unroll
      for (int e = 0; e < 8; ++e) fr[e] = (h16)p[e];
      whhf[kk][j] = fr;
    }
  }
  const float bias0 = bih[row0] + bhh[row0];
  const float bias1 = bih[row1] + bhh[row1];
  float c[4] = {0.f, 0.f, 0.f, 0.f};
  const bool hi = (lane & 8) != 0;

  #pragma unroll 1
  for (int t = 0; t < 512; ++t){
    // ================= phase 1: input from layer below =================
    if (!XSRC && tid == 0)
      wait_flag16((const unsigned long long*)(flagSrc + (size_t)t*16));
    __syncthreads();

    if constexpr (XSRC){
      #pragma unroll
      for (int i = 0; i < 2; ++i){
        int q = tid + i*256;
        int row = q >> 5, col = q & 31;          // 32 chunks x 8 halves per row
        const float* xp = xsrc + ((size_t)(bg*16 + row)*512 + t)*256 + col*8;
        float4 v0 = *(const float4*)(xp);
        float4 v1 = *(const float4*)(xp + 4);
        v8h o = {(h16)v0.x,(h16)v0.y,(h16)v0.z,(h16)v0.w,
                 (h16)v1.x,(h16)v1.y,(h16)v1.z,(h16)v1.w};
        *(v8h*)(A + row*ISTR + col*8) = o;
      }
    } else {
      unsigned long long a0[4], a1[4];
      #pragma unroll
      for (int i = 0; i < 4; ++i){
        int q = tid + i*256;
        int row = q >> 6, col = q & 63;          // 64 chunks x 8 halves per row
        const h16* sp = src + ((size_t)t*64 + bg*16 + row)*512 + col*8;
        a0[i] = cload64(sp);
        a1[i] = cload64(sp + 4);
      }
      #pragma unroll
      for (int i = 0; i < 4; ++i){
        int q = tid + i*256;
        int row = q >> 6, col = q & 63;
        union { unsigned long long u[2]; v8h h; } tmp;
        tmp.u[0] = a0[i]; tmp.u[1] = a1[i];
        *(v8h*)(A + row*ISTR + col*8) = tmp.h;
      }
    }
    __syncthreads();

    // pre-check self flag; its L3 latency hides behind the W_ih MFMA chain
    unsigned long long pa = FPAT, pb = FPAT;
    if (tid == 0 && t > 0){
      const unsigned long long* fs =
          (const unsigned long long*)(flagSelf + (size_t)(t-1)*16);
      pa = cload64(fs);
      pb = cload64(fs + 1);
    }

    v4f acc0 = {0.f, 0.f, 0.f, 0.f};
    v4f acc1 = {0.f, 0.f, 0.f, 0.f};
    const h16* Ain = A + n16*ISTR + ksub;
    #pragma unroll
    for (int kk = 0; kk < KI; ++kk){
      v8h a = *(const v8h*)(Ain + kk*32);
      acc0 = __builtin_amdgcn_mfma_f32_16x16x32_f16(a, wihf[kk][0], acc0, 0, 0, 0);
      acc1 = __builtin_amdgcn_mfma_f32_16x16x32_f16(a, wihf[kk][1], acc1, 0, 0, 0);
    }

    // ================= phase 2: recurrence =================
    if (tid == 0 && t > 0 && (pa & pb) != FPAT)
      wait_flag16((const unsigned long long*)(flagSelf + (size_t)(t-1)*16));
    __syncthreads();

    if (t == 0){
      #pragma unroll
      for (int i = 0; i < 4; ++i){
        int q = tid + i*256;
        int row = q >> 6, col = q & 63;
        union { unsigned long long u[2]; v8h h; } tmp;
        tmp.u[0] = 0ull; tmp.u[1] = 0ull;
        *(v8h*)(A + HOFF + row*520 + col*8) = tmp.h;
      }
    } else {
      const h16* hsrc = dst + (size_t)((t-1) & dstMask) * 64 * 512;
      unsigned long long a0[4], a1[4];
      #pragma unroll
      for (int i = 0; i < 4; ++i){
        int q = tid + i*256;
        int row = q >> 6, col = q & 63;
        const h16* sp = hsrc + (size_t)(bg*16 + row)*512 + col*8;
        a0[i] = cload64(sp);
        a1[i] = cload64(sp + 4);
      }
      #pragma unroll
      for (int i = 0; i < 4; ++i){
        int q = tid + i*256;
        int row = q >> 6, col = q & 63;
        union { unsigned long long u[2]; v8h h; } tmp;
        tmp.u[0] = a0[i]; tmp.u[1] = a1[i];
        *(v8h*)(A + HOFF + row*520 + col*8) = tmp.h;
      }
    }
    __syncthreads();

    const h16* Ah = A + HOFF + n16*520 + ksub;
    #pragma unroll
    for (int kk = 0; kk < 16; ++kk){
      v8h a = *(const v8h*)(Ah + kk*32);
      acc0 = __builtin_amdgcn_mfma_f32_16x16x32_f16(a, whhf[kk][0], acc0, 0, 0, 0);
      acc1 = __builtin_amdgcn_mfma_f32_16x16x32_f16(a, whhf[kk][1], acc1, 0, 0, 0);
    }

    // ---- gates: lane L holds (i|f) in acc0, (g|o) in acc1; partner is L^8
    h16* drow = dst + (size_t)(t & dstMask) * 64 * 512;
    #pragma unroll
    for (int r = 0; r < 4; ++r){
      float z0 = acc0[r] + bias0;
      float z1 = acc1[r] + bias1;
      float p0 = __shfl_xor(z0, 8, 64);
      float p1 = __shfl_xor(z1, 8, 64);
      float iv = hi ? p0 : z0;
      float fv = hi ? z0 : p0;
      float gv = hi ? p1 : z1;
      float ov = hi ? z1 : p1;
      iv = fsigmoid(iv); fv = fsigmoid(fv); ov = fsigmoid(ov);
      gv = ftanhf(gv);
      c[r] = fv * c[r] + iv * gv;
      float hval = ov * ftanhf(c[r]);
      h16 hh = (h16)hval;
      unsigned int mine = (unsigned int)__builtin_bit_cast(unsigned short, hh);
      unsigned int partner = (unsigned int)__shfl_xor((int)mine, 1, 64);
      if (!hi && !(n16 & 1)){
        int batch = bg*16 + ((lane >> 4) << 2) + r;
        // packed 2-unit write-through store (sc0 sc1) -> visible in L3
        cstore32((void*)(drow + (size_t)batch*512 + unit), mine | (partner << 16));
      }
    }
    __syncthreads();   // each wave's vmcnt(0) drains write-through stores to L3

    // publish: one independent fire-and-forget byte store per wg — the 16
    // producer bytes commit in parallel at the coherence point (no RMW chain).
    if (tid == 0)
      cstore8(flagSelf + (size_t)t*16 + rg, 1);
  }
}

__global__ __launch_bounds__(256, 1) void lstm_persist(PParams p){
  __shared__ h16 A[16640];   // 33,280 B: in-region 16x520 + h-region 16x520
  const int bx = blockIdx.x;
  const int l  = bx >> 6;
  const int rg = (bx >> 2) & 15;
  const int bg = bx & 3;
  unsigned char* fl = p.flags + (size_t)(l*4 + bg) * 512 * 16;
  if (l == 0){
    run_layer<256, true >(p.Wih[0], p.Whh[0], p.bih[0], p.bhh[0], p.x, nullptr,
                          p.s[0], 511, fl, nullptr, rg, bg, A);
  } else {
    const unsigned char* fs = p.flags + (size_t)((l-1)*4 + bg) * 512 * 16;
    run_layer<512, false>(p.Wih[l], p.Whh[l], p.bih[l], p.bhh[l], nullptr, p.s[l-1],
                          p.s[l], (l == 3) ? 1 : 511, fl, fs, rg, bg, A);
  }
}

__global__ void head_k(const h16* __restrict__ h3, const float* __restrict__ Wo,
                       const float* __restrict__ bo, float* __restrict__ out){
  const int b = blockIdx.x;
  const int lane = threadIdx.x;
  float s = 0.f;
  for (int u = lane; u < 512; u += 64)
    s += (float)h3[(size_t)b * 512 + u] * Wo[u];
  #pragma unroll
  for (int off = 32; off; off >>= 1) s += __shfl_down(s, off, 64);
  if (lane == 0) out[b] = s + bo[0];
}

__global__ void zero_out_k(float* out, int n){
  int i = blockIdx.x * 64 + threadIdx.x;
  if (i < n) out[i] = 0.f;
}

extern "C" void kernel_launch(void* const* d_in, const int* in_sizes, int n_in,
                              void* d_out, int out_size, void* d_ws, size_t ws_size,
                              hipStream_t stream){
  PParams p;
  p.x = (const float*)d_in[0];
  for (int l = 0; l < 4; ++l){
    p.Wih[l] = (const float*)d_in[1 + 4*l + 0];
    p.Whh[l] = (const float*)d_in[1 + 4*l + 1];
    p.bih[l] = (const float*)d_in[1 + 4*l + 2];
    p.bhh[l] = (const float*)d_in[1 + 4*l + 3];
  }
  const float* Wo = (const float*)d_in[17];
  const float* bo = (const float*)d_in[18];

  const size_t FLAG_BYTES = (size_t)16 * 512 * 16;                // 128 KB
  const size_t SBYTES     = (size_t)512 * 64 * 512 * 2;           // 32 MB per full stream
  const size_t NEED       = FLAG_BYTES + 3 * SBYTES + (size_t)2 * 64 * 512 * 2;

  if (ws_size < NEED){
    zero_out_k<<<dim3(1), dim3(64), 0, stream>>>((float*)d_out, out_size);
    return;
  }

  char* ws = (char*)d_ws;
  p.flags = (unsigned char*)ws;
  size_t off = FLAG_BYTES;
  for (int l = 0; l < 3; ++l){ p.s[l] = (h16*)(ws + off); off += SBYTES; }
  p.s[3] = (h16*)(ws + off);

  hipMemsetAsync(p.flags, 0, FLAG_BYTES, stream);

  void* args[] = { &p };
  hipError_t e = hipLaunchCooperativeKernel((void*)lstm_persist, dim3(256), dim3(256),
                                            args, 0, stream);
  if (e != hipSuccess){
    // fallback: plain launch; 256 blocks @ 1 wg/CU co-reside on 256 CUs
    lstm_persist<<<dim3(256), dim3(256), 0, stream>>>(p);
  }

  // final timestep t=511 lives in s3 buffer (511 & 1) == 1
  head_k<<<dim3(64), dim3(64), 0, stream>>>(p.s[3] + (size_t)64 * 512, Wo, bo, (float*)d_out);
}